// Round 5
// baseline (423.458 us; speedup 1.0000x reference)
//
#include <hip/hip_runtime.h>

#define N_V  20000
#define B_   8
#define F_   64
#define K_   6
#define OUT_ 64
#define NNZ_ 320000
#define BF   512    // B_*F_
#define NBUK N_V                    // one bucket per row
#define SCANB 20                    // ceil(NBUK/1024)
#define EPAD (NNZ_ + N_V * 7)       // buckets padded to multiple of 8 edges

typedef unsigned short ushort_t;
typedef unsigned int   uint_t;

using frag_ab = __attribute__((ext_vector_type(8))) short;  // 8 bf16 (4 VGPRs)
using frag_cd = __attribute__((ext_vector_type(4))) float;  // 4 f32 acc

// ---- bf16 helpers ----
__device__ __forceinline__ ushort_t f2bf(float f) {          // round-to-nearest-even
    uint_t u = __float_as_uint(f);
    u += 0x7FFFu + ((u >> 16) & 1u);
    return (ushort_t)(u >> 16);
}
__device__ __forceinline__ uint_t pack2(float lo, float hi) {
    return (uint_t)f2bf(lo) | ((uint_t)f2bf(hi) << 16);
}
__device__ __forceinline__ void unpack2(uint_t u, float& lo, float& hi) {
    lo = __uint_as_float(u << 16);
    hi = __uint_as_float(u & 0xFFFF0000u);
}

// -------- bucketed build: one bucket per row, padded to multiple of 8 --------

__global__ void hist_kernel(const int* __restrict__ rows, int* __restrict__ counts) {
    int e = blockIdx.x * 256 + threadIdx.x;
    if (e < NNZ_) atomicAdd(&counts[rows[e]], 1);
}

__global__ __launch_bounds__(1024) void scan1(const int* __restrict__ counts,
                                              int* __restrict__ incl, int* __restrict__ bsum) {
    __shared__ int buf[1024];
    int tid = threadIdx.x;
    int i = blockIdx.x * 1024 + tid;
    int c = (i < NBUK) ? ((counts[i] + 7) & ~7) : 0;   // padded count
    buf[tid] = c;
    __syncthreads();
    for (int off = 1; off < 1024; off <<= 1) {
        int t = buf[tid];
        int add = (tid >= off) ? buf[tid - off] : 0;
        __syncthreads();
        buf[tid] = t + add;
        __syncthreads();
    }
    if (i < NBUK) incl[i] = buf[tid];
    if (tid == 1023) bsum[blockIdx.x] = buf[1023];
}

__global__ __launch_bounds__(256) void scan2(int* __restrict__ bsum) {
    __shared__ int buf[256];
    int tid = threadIdx.x;
    int c = (tid < SCANB) ? bsum[tid] : 0;
    buf[tid] = c;
    __syncthreads();
    for (int off = 1; off < 256; off <<= 1) {
        int t = buf[tid];
        int add = (tid >= off) ? buf[tid - off] : 0;
        __syncthreads();
        buf[tid] = t + add;
        __syncthreads();
    }
    if (tid < SCANB) bsum[tid] = buf[tid] - c;   // exclusive block offsets
}

__global__ __launch_bounds__(1024) void scan3(const int* __restrict__ counts,
                                              const int* __restrict__ bsum,
                                              int* __restrict__ bp, int* __restrict__ cursor) {
    int tid = threadIdx.x;
    int i = blockIdx.x * 1024 + tid;
    if (i < NBUK) {
        int pc = (counts[i] + 7) & ~7;
        int p = bsum[blockIdx.x] + cursor[i];   // global inclusive prefix (padded)
        bp[i + 1] = p;
        cursor[i] = p - pc;                     // bucket start for scatter
    }
    if (i == 0) bp[0] = 0;
}

// edges packed: {col, val_bits}; pad slots stay {0, 0.0f} from memset (zero contribution)
__global__ void scatter_kernel(const int* __restrict__ rows, const int* __restrict__ cols,
                               const float* __restrict__ vals, int* __restrict__ cursor,
                               int2* __restrict__ edges) {
    int e = blockIdx.x * 256 + threadIdx.x;
    if (e < NNZ_) {
        int pos = atomicAdd(&cursor[rows[e]], 1);
        edges[pos] = make_int2(cols[e], __float_as_int(vals[e]));
    }
}

// ---------------- fat prep: x->X0 bf16 (T layout [n][b][f]) + Wfrag pack ----------------
__global__ void prep_kernel(const float* __restrict__ x, uint_t* __restrict__ X0,
                            const float* __restrict__ W, ushort_t* __restrict__ Wfrag) {
    int blk = blockIdx.x;
    if (blk < 20000) {
        int idx = blk * 256 + threadIdx.x;      // over N_V*B_*32
        int f2 = idx & 31;
        int b  = (idx >> 5) & 7;
        int n  = idx >> 8;
        float2 v = *(const float2*)&x[((size_t)b * N_V + n) * F_ + f2 * 2];
        X0[n * 256 + b * 32 + f2] = pack2(v.x, v.y);
    } else {
        int idx = (blk - 20000) * 256 + threadIdx.x;
        if (idx < 12 * 4 * 64 * 8) {
            int j    = idx & 7;
            int lane = (idx >> 3) & 63;
            int ct   = (idx >> 9) & 3;
            int s    = idx >> 11;
            int o     = ct * 16 + (lane & 15);
            int kglob = s * 32 + ((lane >> 4) & 3) * 8 + j;
            Wfrag[idx] = f2bf(W[o * (K_ * F_) + kglob]);
        }
    }
}

// -------- SpMM: 2 rows/wave, 8 edges/iter, 16B/lane gathers, XCD-chunked --------
// chunk = blockIdx & 7 -> XCD affinity; per-XCD gather footprint = 2.56 MB (fits 4 MB L2).
// Lane l: edge sub = l>>3 of the iteration, features (l&7)*8 .. +8 of the chunk.
// One gather instruction = 8 edges x 128 B (uint4/lane). One int2 edge load per iter
// (8-lane groups share a cacheline). Gathers pipelined 2 iterations deep.
template <bool RECUR>
__global__ __launch_bounds__(256) void cheb_row8(const int* __restrict__ bp,
                                                 const int2* __restrict__ edges,
                                                 const ushort_t* __restrict__ Tprev,
                                                 const ushort_t* __restrict__ Tpp,
                                                 ushort_t* __restrict__ Tout) {
    const int wave = threadIdx.x >> 6, lane = threadIdx.x & 63;
    const int c    = blockIdx.x & 7;                   // chunk == batch index == XCD slot
    const int pair = (blockIdx.x >> 3) * 4 + wave;     // [0, 10000)
    const int r0   = pair * 2;
    const int sub  = lane >> 3;                        // edge slot 0..7 within iteration
    const int f8   = (lane & 7) << 3;                  // 8 features per lane

    const int st  = bp[r0];
    const int mid = bp[r0 + 1];
    const int en  = bp[r0 + 2];

    const ushort_t* Tb = Tprev + (c << 6) + f8;        // + col*512 per edge
    const int2*    eb  = edges + sub;

    float aA0 = 0.f, aA1 = 0.f, aA2 = 0.f, aA3 = 0.f,
          aA4 = 0.f, aA5 = 0.f, aA6 = 0.f, aA7 = 0.f;  // row 2p
    float aB0 = 0.f, aB1 = 0.f, aB2 = 0.f, aB3 = 0.f,
          aB4 = 0.f, aB5 = 0.f, aB6 = 0.f, aB7 = 0.f;  // row 2p+1

    if (st < en) {
        const int lim = en - 8;                        // last valid block start
        // pipeline: E holds edges for j, j+8, j+16; G holds gathers for j, j+8
        int2 E0 = eb[st];
        int2 E1 = eb[min(st + 8, lim)];
        int2 E2 = eb[min(st + 16, lim)];
        uint4 G0 = *(const uint4*)(Tb + ((size_t)(uint_t)E0.x << 9));
        uint4 G1 = *(const uint4*)(Tb + ((size_t)(uint_t)E1.x << 9));
        float v0 = __int_as_float(E0.y);
        float v1 = __int_as_float(E1.y);

        for (int j = st; j < en; j += 8) {
            // issue gather for j+16 (edge data loaded 2 iterations ago)
            uint4 Gn = *(const uint4*)(Tb + ((size_t)(uint_t)E2.x << 9));
            float vn = __int_as_float(E2.y);
            // load edges for j+24 (clamped)
            int2 En = eb[min(j + 24, lim)];
            // consume j: waits only G0 (4 younger vmem ops stay in flight)
            float e0, e1, e2, e3, e4, e5, e6, e7;
            unpack2(G0.x, e0, e1); unpack2(G0.y, e2, e3);
            unpack2(G0.z, e4, e5); unpack2(G0.w, e6, e7);
            if (j < mid) {                             // wave-uniform branch
                aA0 = fmaf(v0, e0, aA0); aA1 = fmaf(v0, e1, aA1);
                aA2 = fmaf(v0, e2, aA2); aA3 = fmaf(v0, e3, aA3);
                aA4 = fmaf(v0, e4, aA4); aA5 = fmaf(v0, e5, aA5);
                aA6 = fmaf(v0, e6, aA6); aA7 = fmaf(v0, e7, aA7);
            } else {
                aB0 = fmaf(v0, e0, aB0); aB1 = fmaf(v0, e1, aB1);
                aB2 = fmaf(v0, e2, aB2); aB3 = fmaf(v0, e3, aB3);
                aB4 = fmaf(v0, e4, aB4); aB5 = fmaf(v0, e5, aB5);
                aB6 = fmaf(v0, e6, aB6); aB7 = fmaf(v0, e7, aB7);
            }
            // shift pipeline
            G0 = G1; v0 = v1; G1 = Gn; v1 = vn; E2 = En;
        }
    }

    // reduce across the 8 edge-subgroups (xor 8, 16, 32)
#define RED(x) x += __shfl_xor(x, 8, 64); x += __shfl_xor(x, 16, 64); x += __shfl_xor(x, 32, 64)
    RED(aA0); RED(aA1); RED(aA2); RED(aA3); RED(aA4); RED(aA5); RED(aA6); RED(aA7);
    RED(aB0); RED(aB1); RED(aB2); RED(aB3); RED(aB4); RED(aB5); RED(aB6); RED(aB7);
#undef RED

    if (lane < 16) {
        const int isB = lane >> 3;                     // lanes 0-7: row r0; 8-15: row r0+1
        float s0 = isB ? aB0 : aA0;
        float s1 = isB ? aB1 : aA1;
        float s2 = isB ? aB2 : aA2;
        float s3 = isB ? aB3 : aA3;
        float s4 = isB ? aB4 : aA4;
        float s5 = isB ? aB5 : aA5;
        float s6 = isB ? aB6 : aA6;
        float s7 = isB ? aB7 : aA7;
        const size_t o = (size_t)(r0 + isB) * BF + (c << 6) + f8;
        if (RECUR) {
            uint4 up = *(const uint4*)(Tpp + o);
            float p0, p1, p2, p3, p4, p5, p6, p7;
            unpack2(up.x, p0, p1); unpack2(up.y, p2, p3);
            unpack2(up.z, p4, p5); unpack2(up.w, p6, p7);
            s0 = fmaf(2.f, s0, -p0); s1 = fmaf(2.f, s1, -p1);
            s2 = fmaf(2.f, s2, -p2); s3 = fmaf(2.f, s3, -p3);
            s4 = fmaf(2.f, s4, -p4); s5 = fmaf(2.f, s5, -p5);
            s6 = fmaf(2.f, s6, -p6); s7 = fmaf(2.f, s7, -p7);
        }
        uint4 st4;
        st4.x = pack2(s0, s1);
        st4.y = pack2(s2, s3);
        st4.z = pack2(s4, s5);
        st4.w = pack2(s6, s7);
        *(uint4*)(Tout + o) = st4;
    }
}

// ---------------- FC via MFMA 16x16x32 bf16, 2 tiles/wave ----------------
__global__ __launch_bounds__(256) void fc_mfma(const ushort_t* __restrict__ X0,
                                               const ushort_t* __restrict__ T1,
                                               const ushort_t* __restrict__ T2,
                                               const ushort_t* __restrict__ T3,
                                               const ushort_t* __restrict__ T4,
                                               const ushort_t* __restrict__ T5,
                                               const ushort_t* __restrict__ Wfrag,
                                               const float* __restrict__ bias,
                                               float* __restrict__ out) {
    const int wave = threadIdx.x >> 6, lane = threadIdx.x & 63;
    const int quad = lane >> 4, col = lane & 15;
    const int tb = blockIdx.x * 128 + wave * 32;      // 2 tiles: tb, tb+16
    const int r0 = tb + col, r1 = tb + 16 + col;
    const ushort_t* Tbuf[6] = {X0, T1, T2, T3, T4, T5};

    frag_cd acc0[4], acc1[4];
#pragma unroll
    for (int ct = 0; ct < 4; ++ct) {
        acc0[ct] = (frag_cd){0.f, 0.f, 0.f, 0.f};
        acc1[ct] = (frag_cd){0.f, 0.f, 0.f, 0.f};
    }

#pragma unroll
    for (int s = 0; s < 12; ++s) {
        const int f0 = (s & 1) * 32 + quad * 8;
        frag_ab fa0 = *(const frag_ab*)(Tbuf[s >> 1] + (size_t)r0 * F_ + f0);
        frag_ab fa1 = *(const frag_ab*)(Tbuf[s >> 1] + (size_t)r1 * F_ + f0);
#pragma unroll
        for (int ct = 0; ct < 4; ++ct) {
            frag_ab bfr = *(const frag_ab*)(Wfrag + (((s * 4 + ct) * 64 + lane) << 3));
            acc0[ct] = __builtin_amdgcn_mfma_f32_16x16x32_bf16(fa0, bfr, acc0[ct], 0, 0, 0);
            acc1[ct] = __builtin_amdgcn_mfma_f32_16x16x32_bf16(fa1, bfr, acc1[ct], 0, 0, 0);
        }
    }

    // C/D: col = lane&15, row = quad*4 + reg
#pragma unroll
    for (int ct = 0; ct < 4; ++ct) {
        const int o = ct * 16 + col;
        const float bv = bias[o];
#pragma unroll
        for (int reg = 0; reg < 4; ++reg) {
            int ra = tb + quad * 4 + reg;
            int rb = ra + 16;
            out[(size_t)(ra & 7) * N_V * OUT_ + (size_t)(ra >> 3) * OUT_ + o] = acc0[ct][reg] + bv;
            out[(size_t)(rb & 7) * N_V * OUT_ + (size_t)(rb >> 3) * OUT_ + o] = acc1[ct][reg] + bv;
        }
    }
}

// ---------------- launcher ----------------

extern "C" void kernel_launch(void* const* d_in, const int* in_sizes, int n_in,
                              void* d_out, int out_size, void* d_ws, size_t ws_size,
                              hipStream_t stream) {
    const float* x    = (const float*)d_in[0];
    const int*   rows = (const int*)  d_in[1];
    const int*   cols = (const int*)  d_in[2];
    const float* vals = (const float*)d_in[3];
    const float* W    = (const float*)d_in[4];
    const float* bias = (const float*)d_in[5];
    float* out = (float*)d_out;

    const size_t TSZ = (size_t)N_V * BF;           // bf16 elements per T buffer
    ushort_t* T1 = (ushort_t*)d_ws;
    ushort_t* T2 = T1 + TSZ;
    ushort_t* T3 = T2 + TSZ;
    ushort_t* T4 = T3 + TSZ;
    ushort_t* T5 = T4 + TSZ;
    ushort_t* X0 = T5 + TSZ;
    ushort_t* Wfrag = X0 + TSZ;                    // 24576 ushorts
    int* counts    = (int*)(Wfrag + 24576);        // NBUK
    int* bp        = counts + NBUK;                // NBUK+1 (+pad)
    int* cursor    = bp + NBUK + 64;               // NBUK
    int* bsum      = cursor + NBUK;                // 256
    int2* edges    = (int2*)(bsum + 256);          // EPAD int2 (zero-padded)

    hipMemsetAsync(counts, 0, NBUK * sizeof(int), stream);
    hipMemsetAsync(edges, 0, (size_t)EPAD * sizeof(int2), stream);
    hist_kernel<<<(NNZ_ + 255) / 256, 256, 0, stream>>>(rows, counts);
    scan1<<<SCANB, 1024, 0, stream>>>(counts, cursor, bsum);
    scan2<<<1, 256, 0, stream>>>(bsum);
    scan3<<<SCANB, 1024, 0, stream>>>(counts, bsum, bp, cursor);
    scatter_kernel<<<(NNZ_ + 255) / 256, 256, 0, stream>>>(rows, cols, vals, cursor, edges);
    prep_kernel<<<20096, 256, 0, stream>>>(x, (uint_t*)X0, W, Wfrag);

    const int chebGrid = 2500 * 8;                 // (pairgroup of 4 waves) x 8 chunks
    cheb_row8<false><<<chebGrid, 256, 0, stream>>>(bp, edges, X0, nullptr, T1);
    cheb_row8<true ><<<chebGrid, 256, 0, stream>>>(bp, edges, T1, X0, T2);
    cheb_row8<true ><<<chebGrid, 256, 0, stream>>>(bp, edges, T2, T1, T3);
    cheb_row8<true ><<<chebGrid, 256, 0, stream>>>(bp, edges, T3, T2, T4);
    cheb_row8<true ><<<chebGrid, 256, 0, stream>>>(bp, edges, T4, T3, T5);

    fc_mfma<<<(N_V * B_) / 128, 256, 0, stream>>>(X0, T1, T2, T3, T4, T5, Wfrag, bias, out);
}